// Round 2
// baseline (1637.357 us; speedup 1.0000x reference)
//
#include <hip/hip_runtime.h>
#include <stdint.h>

#define NROWS 32768
#define KP    4000
#define DIM   128
#define CL    1000
#define NCHUNKS 4
#define KCHUNK  (KP / NCHUNKS)     // 1000
#define TK      32                 // proxies per LDS tile
#define RPB     128                // rows per block (256 threads, 2/row)

// Map float to u32 with same total order (handles negatives).
__device__ __forceinline__ unsigned int f2ord(float f) {
    unsigned int u = __float_as_uint(f);
    return (u & 0x80000000u) ? ~u : (u | 0x80000000u);
}

// 16B async global->LDS. LDS dest must be wave-uniform; HW adds lane*16.
__device__ __forceinline__ void async_copy16(const float* gsrc, float* ldst) {
    __builtin_amdgcn_global_load_lds(
        (const __attribute__((address_space(1))) unsigned int*)gsrc,
        (__attribute__((address_space(3))) unsigned int*)ldst,
        16, 0, 0);
}

// p2[k] = ||proxies[k]||^2 ; packed[n] init to u64 max (ws is poisoned)
__global__ void init_kernel(unsigned long long* __restrict__ packed,
                            float* __restrict__ p2,
                            const float* __restrict__ proxies) {
    int i = blockIdx.x * blockDim.x + threadIdx.x;
    if (i < NROWS) packed[i] = 0xFFFFFFFFFFFFFFFFull;
    if (i < KP) {
        const float4* p = (const float4*)(proxies + (long)i * DIM);
        float s = 0.f;
        #pragma unroll
        for (int d = 0; d < DIM / 4; d++) {
            float4 v = p[d];
            s = fmaf(v.x, v.x, s); s = fmaf(v.y, v.y, s);
            s = fmaf(v.z, v.z, s); s = fmaf(v.w, v.w, s);
        }
        p2[i] = s;
    }
}

// 2 threads per row: thread holds 64 x-floats (16 float4 = 64 VGPR).
// Proxies double-buffered in LDS via global_load_lds; per-k pair reduce
// via shfl_xor. score = p2[k] - 2*dot (monotone in true distance).
__global__ void __launch_bounds__(256, 4)
argmin_kernel(const float* __restrict__ x,
              const float* __restrict__ proxies,
              const float* __restrict__ p2,
              unsigned long long* __restrict__ packed) {
    __shared__ float sP[2][TK * DIM];   // 2 x 16 KB
    __shared__ float sp2[2][TK];

    const int tid  = threadIdx.x;
    const int lane = tid & 63;
    const int wave = tid >> 6;          // 4 waves
    const int half = tid & 1;
    const int row  = blockIdx.x * RPB + (tid >> 1);
    const int kb0  = blockIdx.y * KCHUNK;

    // x half-row into VGPRs (strided per lane; L1 serves re-hits across i)
    float4 xr[16];
    const float4* xp = (const float4*)(x + (long)row * DIM + half * 64);
    #pragma unroll
    for (int i = 0; i < 16; i++) xr[i] = xp[i];

    const int ntiles = (KCHUNK + TK - 1) / TK;   // 32 (31 full + tail 8)

    // ---- stage tile 0 into buf 0 ----
    {
        int klen = (KCHUNK < TK) ? KCHUNK : TK;
        float v = 0.f;
        if (tid < klen) v = p2[kb0 + tid];
        const float* gbase = proxies + (long)kb0 * DIM;
        #pragma unroll
        for (int r = 0; r < 4; r++) {
            int j = wave * 256 + r * 64;          // float4 index, wave-uniform
            if (j < klen * 32)
                async_copy16(gbase + (long)(j + lane) * 4, &sP[0][(long)j * 4]);
        }
        if (tid < klen) sp2[0][tid] = v;
    }
    __syncthreads();   // barrier drains vmcnt -> tile 0 landed

    float best = 3.4e38f;
    int bestk = kb0;

    for (int t = 0; t < ntiles; t++) {
        const int cur = t & 1, nxt = cur ^ 1;
        const int kb = kb0 + t * TK;
        const int klen = min(TK, kb0 + KCHUNK - kb);

        // prefetch tile t+1 into nxt (async; drained by trailing barrier)
        if (t + 1 < ntiles) {
            int kb2 = kb + TK;
            int klen2 = min(TK, kb0 + KCHUNK - kb2);
            float v = 0.f;
            if (tid < klen2) v = p2[kb2 + tid];   // issue before glds (FIFO)
            const float* gbase = proxies + (long)kb2 * DIM;
            #pragma unroll
            for (int r = 0; r < 4; r++) {
                int j = wave * 256 + r * 64;
                if (j < klen2 * 32)
                    async_copy16(gbase + (long)(j + lane) * 4, &sP[nxt][(long)j * 4]);
            }
            if (tid < klen2) sp2[nxt][tid] = v;
        }

        // compute tile t
        for (int kk = 0; kk < klen; kk++) {
            const float4* pr = (const float4*)&sP[cur][kk * DIM + half * 64];
            float a0 = 0.f, a1 = 0.f, a2 = 0.f, a3 = 0.f;
            #pragma unroll
            for (int i = 0; i < 16; i += 4) {
                float4 q0 = pr[i], q1 = pr[i + 1], q2 = pr[i + 2], q3 = pr[i + 3];
                a0 = fmaf(xr[i  ].x, q0.x, a0); a0 = fmaf(xr[i  ].y, q0.y, a0);
                a0 = fmaf(xr[i  ].z, q0.z, a0); a0 = fmaf(xr[i  ].w, q0.w, a0);
                a1 = fmaf(xr[i+1].x, q1.x, a1); a1 = fmaf(xr[i+1].y, q1.y, a1);
                a1 = fmaf(xr[i+1].z, q1.z, a1); a1 = fmaf(xr[i+1].w, q1.w, a1);
                a2 = fmaf(xr[i+2].x, q2.x, a2); a2 = fmaf(xr[i+2].y, q2.y, a2);
                a2 = fmaf(xr[i+2].z, q2.z, a2); a2 = fmaf(xr[i+2].w, q2.w, a2);
                a3 = fmaf(xr[i+3].x, q3.x, a3); a3 = fmaf(xr[i+3].y, q3.y, a3);
                a3 = fmaf(xr[i+3].z, q3.z, a3); a3 = fmaf(xr[i+3].w, q3.w, a3);
            }
            float dot = (a0 + a1) + (a2 + a3);
            float tot = dot + __shfl_xor(dot, 1);   // both lanes get same bits
            float score = fmaf(-2.f, tot, sp2[cur][kk]);
            if (score < best) { best = score; bestk = kb + kk; }  // first-min
        }
        __syncthreads();   // readers done with cur + prefetch landed in nxt
    }

    if (half == 0) {
        unsigned long long key =
            ((unsigned long long)f2ord(best) << 32) | (unsigned int)bestk;
        atomicMin(&packed[row], key);   // ties -> smaller k
    }
}

// Fused epilogue: out = [x | proxies[idx] | labels[idx]] as one stream.
__global__ void out_kernel(const float4* __restrict__ x4,
                           const float4* __restrict__ prox4,
                           const float4* __restrict__ lab4,
                           const unsigned long long* __restrict__ packed,
                           float4* __restrict__ out4) {
    const int R0 = NROWS * (DIM / 4);           // 1,048,576
    const int R1 = 2 * NROWS * (DIM / 4);       // 2,097,152
    const int TOT = R1 + NROWS * (CL / 4);      // 10,289,152
    for (int j = blockIdx.x * blockDim.x + threadIdx.x; j < TOT;
         j += gridDim.x * blockDim.x) {
        if (j < R0) {
            out4[j] = x4[j];
        } else if (j < R1) {
            int m = j - R0;
            int n = m >> 5, d = m & 31;
            int k = (int)(unsigned int)(packed[n] & 0xFFFFFFFFull);
            out4[j] = prox4[(long)k * (DIM / 4) + d];
        } else {
            int m = j - R1;
            int n = m / (CL / 4), d = m % (CL / 4);
            int k = (int)(unsigned int)(packed[n] & 0xFFFFFFFFull);
            out4[j] = lab4[(long)k * (CL / 4) + d];
        }
    }
}

extern "C" void kernel_launch(void* const* d_in, const int* in_sizes, int n_in,
                              void* d_out, int out_size, void* d_ws, size_t ws_size,
                              hipStream_t stream) {
    const float* x       = (const float*)d_in[0];
    const float* proxies = (const float*)d_in[1];
    const float* labels  = (const float*)d_in[2];
    float* out = (float*)d_out;

    float* p2 = (float*)d_ws;                                       // 4000 f
    unsigned long long* packed =
        (unsigned long long*)((char*)d_ws + 16384);                 // 32768 u64

    init_kernel<<<dim3(NROWS / 256), dim3(256), 0, stream>>>(packed, p2, proxies);

    dim3 g(NROWS / RPB, NCHUNKS);   // 256 x 4 = 1024 blocks = 4/CU exactly
    argmin_kernel<<<g, dim3(256), 0, stream>>>(x, proxies, p2, packed);

    out_kernel<<<dim3(2048), dim3(256), 0, stream>>>(
        (const float4*)x, (const float4*)proxies, (const float4*)labels,
        packed, (float4*)out);
}